// Round 11
// baseline (226.190 us; speedup 1.0000x reference)
//
#include <hip/hip_runtime.h>

#define N_NODES  100000
#define N_EDGES  1600000
#define IN_CH    128
#define HID      32
#define N_GRAPHS 64

#define NBIN   391            // bins of 256 dst nodes: bin = dst >> 8
#define CHUNK  4096           // edges per multisplit block; grid = 391
#define MGRID  391            // ceil(1.6M / 4096)
#define BINC   5120           // fixed per-bin capacity in packed edgepk (16-sigma)
#define STG    5120           // csr2 per-bin staging capacity
#define LCAP   2048           // layer_kernel LDS index staging capacity (8 KB)

// workspace layout (4-byte element offsets) — total ~22 MB
#define OFF_B      0          // bf16 B, uint[1,600,000]
#define OFF_EDGEPK 1600000    // int[391*5120 = 2,002,920]; gsum/cnt alias after csr2
#define OFF_CSR    3700000    // int[1,600,000] (dense CSR)
#define OFF_BINCUR 5300000    // int[391]  (atomic bin fill cursors)
#define OFF_BINB   5300391    // int[392]  (dense csr bin bases)
#define OFF_ROWPTR 5300784    // int[100,001]
#define OFF_DINV   5400785    // float[100,000]

// bf16 pack (RNE) / unpack helpers
__device__ __forceinline__ unsigned bfr(float f) {
    unsigned u = __float_as_uint(f);
    u += 0x7fffu + ((u >> 16) & 1u);
    return u >> 16;
}
__device__ __forceinline__ float bflo(unsigned w) { return __uint_as_float(w << 16); }
__device__ __forceinline__ float bfhi(unsigned w) { return __uint_as_float(w & 0xffff0000u); }

// ---------- build A: single-pass multisplit with atomic bin-segment reservation ----------
// Replaces hist + scanrow + scanbase + msplit: each block histograms its CHUNK
// once in LDS, reserves per-bin segments via one global atomicAdd per touched
// bin (bincur L2-resident), then bin-groups edges in LDS and flushes coalesced
// into the fixed-capacity packed array edgepk[bin*BINC + seg].
__global__ __launch_bounds__(512) void msplit2_kernel(const int* __restrict__ src,
                                                      const int* __restrict__ dst,
                                                      int* __restrict__ bincur,
                                                      int* __restrict__ edgepk) {
    __shared__ int s[512];
    __shared__ int cur[NBIN];
    __shared__ int gb[NBIN];
    __shared__ int stage[CHUNK];
    __shared__ int gof[CHUNK];
    int t = threadIdx.x, wg = blockIdx.x;
    s[t] = 0;
    __syncthreads();
    int e0 = wg * CHUNK, e1 = min(e0 + CHUNK, N_EDGES);
    for (int e = e0 + t; e < e1; e += 512) {
        int d = dst[e];
        if ((unsigned)d < N_NODES) atomicAdd(&s[d >> 8], 1);
    }
    __syncthreads();
    for (int off = 1; off < 512; off <<= 1) {
        int v = (t >= off) ? s[t - off] : 0;
        __syncthreads();
        if (t >= off) s[t] += v;
        __syncthreads();
    }
    if (t < NBIN) {
        int lo = t ? s[t - 1] : 0;
        int cnt = s[t] - lo;
        cur[t] = lo;
        int base = cnt ? atomicAdd(&bincur[t], cnt) : 0;
        gb[t] = t * BINC + base - lo;
    }
    __syncthreads();
    for (int e = e0 + t; e < e1; e += 512) {
        int d = dst[e];
        if ((unsigned)d < N_NODES) {
            int b = d >> 8;
            int p = atomicAdd(&cur[b], 1);
            stage[p] = (src[e] << 8) | (d & 255);
            gof[p] = gb[b];
        }
    }
    __syncthreads();
    int total = s[511];
    for (int p = t; p < total; p += 512)
        edgepk[gof[p] + p] = stage[p];
}

// ---------- build B: scan final bin counts -> dense csr bin bases ----------
__global__ __launch_bounds__(512) void scanb_kernel(const int* __restrict__ bincur,
                                                    int* __restrict__ binB,
                                                    int* __restrict__ row_ptr) {
    __shared__ int s[512];
    int t = threadIdx.x;
    s[t] = (t < NBIN) ? bincur[t] : 0;
    __syncthreads();
    for (int off = 1; off < 512; off <<= 1) {
        int v = (t >= off) ? s[t - off] : 0;
        __syncthreads();
        if (t >= off) s[t] += v;
        __syncthreads();
    }
    if (t < NBIN) binB[t] = t ? s[t - 1] : 0;
    if (t == 0) { binB[NBIN] = s[NBIN - 1]; row_ptr[N_NODES] = s[NBIN - 1]; }
}

// ---------- build C: within-bin reorder -> dense CSR + dinv/row_ptr (512 thr) ----------
__global__ __launch_bounds__(512) void csr2_kernel(const int* __restrict__ edgepk,
                                                   const int* __restrict__ binB,
                                                   int* __restrict__ row_ptr,
                                                   float* __restrict__ dinv,
                                                   int* __restrict__ csr) {
    __shared__ int cnt[256], s[256], cur[256];
    __shared__ int stage[STG];
    int t = threadIdx.x, bin = blockIdx.x;
    int obase = binB[bin];
    int n = binB[bin + 1] - obase;
    int pb = bin * BINC;                // packed-source base
    if (t < 256) cnt[t] = 0;
    __syncthreads();
    for (int p = t; p < n; p += 512)
        atomicAdd(&cnt[edgepk[pb + p] & 255], 1);
    __syncthreads();
    if (t < 256) s[t] = cnt[t];
    __syncthreads();
    for (int off = 1; off < 256; off <<= 1) {
        int v = (t >= off && t < 256) ? s[t - off] : 0;
        __syncthreads();
        if (t >= off && t < 256) s[t] += v;
        __syncthreads();
    }
    if (t < 256) {
        int excl = t ? s[t - 1] : 0;
        int node = (bin << 8) + t;
        if (node < N_NODES) {
            dinv[node] = rsqrtf((float)(cnt[t] + 1));
            row_ptr[node] = obase + excl;
        }
        cur[t] = excl;
    }
    __syncthreads();
    for (int p = t; p < n; p += 512) {
        int w = edgepk[pb + p];
        int l = atomicAdd(&cur[w & 255], 1);
        int sv = w >> 8;
        if (l < STG) stage[l] = sv;
        else csr[obase + l] = sv;
    }
    __syncthreads();
    int lim = min(n, STG);
    for (int l = t; l < lim; l += 512)
        csr[obase + l] = stage[l];
}

// ---------- B(bf16) = (x @ W1) * dinv[row], register-tiled (4 ch/thread) ----------
// block 0 also zeroes gsum/cnt (aliased edgepk head, dead after csr2).
#define XS1 132               // 128 + 4 pad
__global__ __launch_bounds__(256) void gemm1_kernel(const float* __restrict__ x,
                                                    const float* __restrict__ W1,
                                                    const float* __restrict__ dinv,
                                                    unsigned* __restrict__ Bu,
                                                    float* __restrict__ gz) {
    __shared__ float Wl[IN_CH * HID];   // 16 KB
    __shared__ float xs[32 * XS1];      // 16.9 KB
    int tid = threadIdx.x;
    if (blockIdx.x == 0)
        for (int q = tid; q < N_GRAPHS * HID + N_GRAPHS; q += 256) gz[q] = 0.f;
    for (int j = tid; j < IN_CH * HID / 4; j += 256)
        ((float4*)Wl)[j] = ((const float4*)W1)[j];
    int row0 = blockIdx.x * 32;         // 100000 % 32 == 0
    const float4* x4 = (const float4*)(x + (size_t)row0 * IN_CH);
    for (int j = tid; j < 32 * IN_CH / 4; j += 256) {
        int r = j >> 5, k4 = j & 31;
        ((float4*)&xs[r * XS1])[k4] = x4[j];
    }
    __syncthreads();
    int r = tid >> 3, cg = (tid & 7) * 4;
    const float* xr = &xs[r * XS1];
    float4 acc = {0.f, 0.f, 0.f, 0.f};
    #pragma unroll 8
    for (int k = 0; k < IN_CH; ++k) {
        float xv = xr[k];
        float4 w = *(const float4*)&Wl[k * HID + cg];
        acc.x += xv * w.x; acc.y += xv * w.y; acc.z += xv * w.z; acc.w += xv * w.w;
    }
    int row = row0 + r;
    float dv = dinv[row];
    uint2 p;
    p.x = bfr(acc.x * dv) | (bfr(acc.y * dv) << 16);
    p.y = bfr(acc.z * dv) | (bfr(acc.w * dv) << 16);
    *(uint2*)&Bu[(size_t)row * 16 + (tid & 7) * 2] = p;
}

// ---------- B(bf16) = (in @ W2) * dinv[row], register-tiled ----------
#define XS2 36                // 32 + 4 pad
__global__ __launch_bounds__(256) void gemm2_kernel(const float* __restrict__ in,
                                                    const float* __restrict__ W2,
                                                    const float* __restrict__ dinv,
                                                    unsigned* __restrict__ Bu) {
    __shared__ float Wl[HID * HID];     // 4 KB
    __shared__ float xs[32 * XS2];      // 4.6 KB
    int tid = threadIdx.x;
    ((float4*)Wl)[tid] = ((const float4*)W2)[tid];
    int row0 = blockIdx.x * 32;
    const float4* in4 = (const float4*)(in + (size_t)row0 * HID);
    {
        int r = tid >> 3, k4 = tid & 7;
        ((float4*)&xs[r * XS2])[k4] = in4[tid];
    }
    __syncthreads();
    int r = tid >> 3, cg = (tid & 7) * 4;
    const float* xr = &xs[r * XS2];
    float4 acc = {0.f, 0.f, 0.f, 0.f};
    #pragma unroll
    for (int k = 0; k < HID; ++k) {
        float xv = xr[k];
        float4 w = *(const float4*)&Wl[k * HID + cg];
        acc.x += xv * w.x; acc.y += xv * w.y; acc.z += xv * w.z; acc.w += xv * w.w;
    }
    int row = row0 + r;
    float dv = dinv[row];
    uint2 p;
    p.x = bfr(acc.x * dv) | (bfr(acc.y * dv) << 16);
    p.y = bfr(acc.z * dv) | (bfr(acc.w * dv) << 16);
    *(uint2*)&Bu[(size_t)row * 16 + (tid & 7) * 2] = p;
}

// ---------- gather layer: LDS-staged indices + uint4 Bu gathers (R6-proven) ----------
__global__ __launch_bounds__(256) void layer_kernel(const unsigned* __restrict__ Bu,
                                                    const int* __restrict__ csr,
                                                    const int* __restrict__ row_ptr,
                                                    const float* __restrict__ dinv,
                                                    const float* __restrict__ bias,
                                                    float* __restrict__ out,
                                                    int relu) {
    __shared__ int sidx[LCAP];          // 8 KB
    int tid = threadIdx.x;
    int n0 = blockIdx.x * 64;           // grid 1563, tail guarded
    int nend = min(n0 + 64, N_NODES);
    int j0 = row_ptr[n0], j1 = row_ptr[nend];
    int nblk = j1 - j0;
    int staged = (nblk <= LCAP);
    if (staged)
        for (int p = tid; p < nblk; p += 256) sidx[p] = csr[j0 + p];
    __syncthreads();
    int node = n0 + (tid >> 2);
    if (node >= N_NODES) return;
    int c4 = tid & 3;                   // owns channels 8*c4 .. 8*c4+7
    const uint4* Br = (const uint4*)Bu; // 4 uint4 per node row
    uint4 sw = Br[(size_t)node * 4 + c4];   // self-loop term
    float a0 = bflo(sw.x), a1 = bfhi(sw.x);
    float a2 = bflo(sw.y), a3 = bfhi(sw.y);
    float a4 = bflo(sw.z), a5 = bfhi(sw.z);
    float a6 = bflo(sw.w), a7 = bfhi(sw.w);
    if (staged) {
        int j = row_ptr[node] - j0, re = row_ptr[node + 1] - j0;
        for (; j + 8 <= re; j += 8) {
            int s0 = sidx[j + 0], s1 = sidx[j + 1], s2 = sidx[j + 2], s3 = sidx[j + 3];
            int s4 = sidx[j + 4], s5 = sidx[j + 5], s6 = sidx[j + 6], s7 = sidx[j + 7];
            uint4 w0 = Br[(size_t)s0 * 4 + c4], w1 = Br[(size_t)s1 * 4 + c4];
            uint4 w2 = Br[(size_t)s2 * 4 + c4], w3 = Br[(size_t)s3 * 4 + c4];
            uint4 w4 = Br[(size_t)s4 * 4 + c4], w5 = Br[(size_t)s5 * 4 + c4];
            uint4 w6 = Br[(size_t)s6 * 4 + c4], w7 = Br[(size_t)s7 * 4 + c4];
            a0 += ((bflo(w0.x) + bflo(w1.x)) + (bflo(w2.x) + bflo(w3.x)))
                + ((bflo(w4.x) + bflo(w5.x)) + (bflo(w6.x) + bflo(w7.x)));
            a1 += ((bfhi(w0.x) + bfhi(w1.x)) + (bfhi(w2.x) + bfhi(w3.x)))
                + ((bfhi(w4.x) + bfhi(w5.x)) + (bfhi(w6.x) + bfhi(w7.x)));
            a2 += ((bflo(w0.y) + bflo(w1.y)) + (bflo(w2.y) + bflo(w3.y)))
                + ((bflo(w4.y) + bflo(w5.y)) + (bflo(w6.y) + bflo(w7.y)));
            a3 += ((bfhi(w0.y) + bfhi(w1.y)) + (bfhi(w2.y) + bfhi(w3.y)))
                + ((bfhi(w4.y) + bfhi(w5.y)) + (bfhi(w6.y) + bfhi(w7.y)));
            a4 += ((bflo(w0.z) + bflo(w1.z)) + (bflo(w2.z) + bflo(w3.z)))
                + ((bflo(w4.z) + bflo(w5.z)) + (bflo(w6.z) + bflo(w7.z)));
            a5 += ((bfhi(w0.z) + bfhi(w1.z)) + (bfhi(w2.z) + bfhi(w3.z)))
                + ((bfhi(w4.z) + bfhi(w5.z)) + (bfhi(w6.z) + bfhi(w7.z)));
            a6 += ((bflo(w0.w) + bflo(w1.w)) + (bflo(w2.w) + bflo(w3.w)))
                + ((bflo(w4.w) + bflo(w5.w)) + (bflo(w6.w) + bflo(w7.w)));
            a7 += ((bfhi(w0.w) + bfhi(w1.w)) + (bfhi(w2.w) + bfhi(w3.w)))
                + ((bfhi(w4.w) + bfhi(w5.w)) + (bfhi(w6.w) + bfhi(w7.w)));
        }
        if (j + 4 <= re) {
            int s0 = sidx[j], s1 = sidx[j + 1], s2 = sidx[j + 2], s3 = sidx[j + 3];
            uint4 w0 = Br[(size_t)s0 * 4 + c4], w1 = Br[(size_t)s1 * 4 + c4];
            uint4 w2 = Br[(size_t)s2 * 4 + c4], w3 = Br[(size_t)s3 * 4 + c4];
            a0 += (bflo(w0.x) + bflo(w1.x)) + (bflo(w2.x) + bflo(w3.x));
            a1 += (bfhi(w0.x) + bfhi(w1.x)) + (bfhi(w2.x) + bfhi(w3.x));
            a2 += (bflo(w0.y) + bflo(w1.y)) + (bflo(w2.y) + bflo(w3.y));
            a3 += (bfhi(w0.y) + bfhi(w1.y)) + (bfhi(w2.y) + bfhi(w3.y));
            a4 += (bflo(w0.z) + bflo(w1.z)) + (bflo(w2.z) + bflo(w3.z));
            a5 += (bfhi(w0.z) + bfhi(w1.z)) + (bfhi(w2.z) + bfhi(w3.z));
            a6 += (bflo(w0.w) + bflo(w1.w)) + (bflo(w2.w) + bflo(w3.w));
            a7 += (bfhi(w0.w) + bfhi(w1.w)) + (bfhi(w2.w) + bfhi(w3.w));
            j += 4;
        }
        for (; j < re; ++j) {
            uint4 w = Br[(size_t)sidx[j] * 4 + c4];
            a0 += bflo(w.x); a1 += bfhi(w.x);
            a2 += bflo(w.y); a3 += bfhi(w.y);
            a4 += bflo(w.z); a5 += bfhi(w.z);
            a6 += bflo(w.w); a7 += bfhi(w.w);
        }
    } else {
        int j = row_ptr[node], re = row_ptr[node + 1];
        for (; j < re; ++j) {
            uint4 w = Br[(size_t)csr[j] * 4 + c4];
            a0 += bflo(w.x); a1 += bfhi(w.x);
            a2 += bflo(w.y); a3 += bfhi(w.y);
            a4 += bflo(w.z); a5 += bfhi(w.z);
            a6 += bflo(w.w); a7 += bfhi(w.w);
        }
    }
    float dv = dinv[node];
    float4 bA = *(const float4*)&bias[8 * c4];
    float4 bB = *(const float4*)&bias[8 * c4 + 4];
    float4 o1, o2;
    o1.x = a0 * dv + bA.x; o1.y = a1 * dv + bA.y;
    o1.z = a2 * dv + bA.z; o1.w = a3 * dv + bA.w;
    o2.x = a4 * dv + bB.x; o2.y = a5 * dv + bB.y;
    o2.z = a6 * dv + bB.z; o2.w = a7 * dv + bB.w;
    if (relu) {
        o1.x = fmaxf(o1.x, 0.f); o1.y = fmaxf(o1.y, 0.f);
        o1.z = fmaxf(o1.z, 0.f); o1.w = fmaxf(o1.w, 0.f);
        o2.x = fmaxf(o2.x, 0.f); o2.y = fmaxf(o2.y, 0.f);
        o2.z = fmaxf(o2.z, 0.f); o2.w = fmaxf(o2.w, 0.f);
    }
    float* orow = out + (size_t)node * HID + 8 * c4;
    *(float4*)orow = o1;
    *(float4*)(orow + 4) = o2;
}

// ---------- per-graph mean-pool: register run-accumulation + span flush ----------
__global__ __launch_bounds__(256) void pool_kernel(const float* __restrict__ h,
                                                   const int* __restrict__ batch,
                                                   float* __restrict__ gsum,
                                                   float* __restrict__ cnt) {
    __shared__ float pool[N_GRAPHS * HID];  // 8 KB
    __shared__ float cntl[N_GRAPHS];
    __shared__ int gmin, gmax;
    int t = threadIdx.x;
    for (int j = t; j < N_GRAPHS * HID; j += 256) pool[j] = 0.f;
    if (t < N_GRAPHS) cntl[t] = 0.f;
    if (t == 0) { gmin = N_GRAPHS; gmax = -1; }
    __syncthreads();
    int start = blockIdx.x * 256;
    int end = min(start + 256, N_NODES);
    int c = t & 31;
    float racc = 0.f;
    int rg = -1, rcnt = 0;
    for (int nb = start + (t >> 5); nb < end; nb += 8) {
        float v = h[(size_t)nb * HID + c];
        int g = batch[nb];
        if (g != rg) {
            if ((unsigned)rg < N_GRAPHS) {
                atomicAdd(&pool[rg * HID + c], racc);
                if (c == 0) {
                    atomicAdd(&cntl[rg], (float)rcnt);
                    atomicMin(&gmin, rg); atomicMax(&gmax, rg);
                }
            }
            rg = g; racc = v; rcnt = 1;
        } else { racc += v; ++rcnt; }
    }
    if ((unsigned)rg < N_GRAPHS) {
        atomicAdd(&pool[rg * HID + c], racc);
        if (c == 0) {
            atomicAdd(&cntl[rg], (float)rcnt);
            atomicMin(&gmin, rg); atomicMax(&gmax, rg);
        }
    }
    __syncthreads();
    int lo = gmin, hi = gmax;
    if (hi >= lo) {
        int span = (hi - lo + 1) * HID;
        for (int j = t; j < span; j += 256)
            atomicAdd(&gsum[lo * HID + j], pool[lo * HID + j]);
        for (int j = t; j <= hi - lo; j += 256)
            atomicAdd(&cnt[lo + j], cntl[lo + j]);
    }
}

__global__ void summary_kernel(const float* __restrict__ gsum, const float* __restrict__ cnt,
                               const float* __restrict__ Ws, const float* __restrict__ bs,
                               float* __restrict__ out) {
    int g = blockIdx.x, c = threadIdx.x;
    float inv = 1.f / fmaxf(cnt[g], 1.f);
    float acc = bs[c];
    #pragma unroll
    for (int k = 0; k < HID; ++k)
        acc += gsum[g * HID + k] * inv * Ws[k * HID + c];
    out[g * HID + c] = acc;
}

extern "C" void kernel_launch(void* const* d_in, const int* in_sizes, int n_in,
                              void* d_out, int out_size, void* d_ws, size_t ws_size,
                              hipStream_t stream) {
    const float* x    = (const float*)d_in[0];
    const int* edge   = (const int*)d_in[1];
    const int* src    = edge;
    const int* dst    = edge + N_EDGES;
    const int* batch  = (const int*)d_in[2];
    const float* W1   = (const float*)d_in[3];
    const float* b1   = (const float*)d_in[4];
    const float* W2   = (const float*)d_in[5];
    const float* b2   = (const float*)d_in[6];
    const float* Ws   = (const float*)d_in[7];
    const float* bs   = (const float*)d_in[8];

    float* ws      = (float*)d_ws;
    unsigned* Bu   = (unsigned*)(ws + OFF_B);   // bf16-packed B
    int*   edgepk  = (int*)(ws + OFF_EDGEPK);   // [391][5120] packed bins
    int*   csr     = (int*)(ws + OFF_CSR);
    int*   bincur  = (int*)(ws + OFF_BINCUR);
    int*   binB    = (int*)(ws + OFF_BINB);
    int*   row_ptr = (int*)(ws + OFF_ROWPTR);
    float* dinv    = ws + OFF_DINV;
    float* gsum    = ws + OFF_EDGEPK;           // aliases edgepk (dead after csr2)
    float* cnt     = gsum + N_GRAPHS * HID;

    float* out     = (float*)d_out;
    float* out_sum = out;
    float* out_h   = out + N_GRAPHS * HID;

    // CSR build: atomic-reservation multisplit -> bin-base scan -> within-bin sort
    hipMemsetAsync(bincur, 0, NBIN * sizeof(int), stream);
    msplit2_kernel<<<MGRID, 512, 0, stream>>>(src, dst, bincur, edgepk);
    scanb_kernel  <<<1,     512, 0, stream>>>(bincur, binB, row_ptr);
    csr2_kernel   <<<NBIN,  512, 0, stream>>>(edgepk, binB, row_ptr, dinv, csr);

    int lgrid = (N_NODES + 63) / 64;   // 1563

    // layer 1 (gemm1 block 0 zeroes gsum/cnt)
    gemm1_kernel<<<N_NODES / 32, 256, 0, stream>>>(x, W1, dinv, Bu, gsum);
    layer_kernel<<<lgrid, 256, 0, stream>>>(Bu, csr, row_ptr, dinv, b1, out_h, 1);

    // layer 2
    gemm2_kernel<<<N_NODES / 32, 256, 0, stream>>>(out_h, W2, dinv, Bu);
    layer_kernel<<<lgrid, 256, 0, stream>>>(Bu, csr, row_ptr, dinv, b2, out_h, 0);

    // pooling + summary
    pool_kernel<<<NBIN, 256, 0, stream>>>(out_h, batch, gsum, cnt);
    summary_kernel<<<N_GRAPHS, HID, 0, stream>>>(gsum, cnt, Ws, bs, out_sum);
}